// Round 5
// baseline (247.350 us; speedup 1.0000x reference)
//
#include <hip/hip_runtime.h>

// out = x * diag (broadcast over last axis). x: 32768 x 4096 f32, diag: 4096 f32.
// Memory-bound streaming kernel. R5: manual 8-deep load batching — issue 8
// independent f32x4 loads into registers BEFORE any dependent store, so each
// wave keeps 128B in flight (guaranteed MLP, not compiler-discretionary).
//  - grid stride (2048 x 256 = 524288) multiple of CH4=1024 -> diag hoisted.
//  - 32-bit indices (n4 = 2^25 fits u32).

#define CH4 1024   // 4096 channels / 4 floats per float4
#define BATCH 8

typedef float f32x4 __attribute__((ext_vector_type(4)));

template <bool HOIST>
__global__ __launch_bounds__(256)
void DiagonalLinear_80960133529733_kernel(const f32x4* __restrict__ x,
                                          const f32x4* __restrict__ diag,
                                          f32x4* __restrict__ out,
                                          unsigned int n4) {
    const unsigned int stride = gridDim.x * blockDim.x;
    unsigned int i = blockIdx.x * blockDim.x + threadIdx.x;

    f32x4 dv;
    if (HOIST) dv = diag[i & (CH4 - 1)];   // channel group constant per thread

    // Batched main loop: 8 loads issued back-to-back, then 8 mul+stores.
    for (; i + (BATCH - 1) * stride < n4; i += BATCH * stride) {
        f32x4 v[BATCH];
#pragma unroll
        for (int k = 0; k < BATCH; ++k)
            v[k] = x[i + (unsigned int)k * stride];
        if (!HOIST) dv = diag[i & (CH4 - 1)];
#pragma unroll
        for (int k = 0; k < BATCH; ++k)
            out[i + (unsigned int)k * stride] = v[k] * dv;
    }
    // Tail
    for (; i < n4; i += stride) {
        f32x4 xv = x[i];
        f32x4 dvv = HOIST ? dv : diag[i & (CH4 - 1)];
        out[i] = xv * dvv;
    }
}

extern "C" void kernel_launch(void* const* d_in, const int* in_sizes, int n_in,
                              void* d_out, int out_size, void* d_ws, size_t ws_size,
                              hipStream_t stream) {
    const float* x    = (const float*)d_in[0];
    const float* diag = (const float*)d_in[1];
    float* out        = (float*)d_out;

    const long long n  = (long long)in_sizes[0];   // 32768*4096
    const unsigned int n4 = (unsigned int)(n / 4); // 2^25, fits u32

    const int block = 256;
    long long want = ((long long)n4 + block - 1) / block;
    int grid = (int)(want < 2048 ? want : 2048);

    const unsigned int stride = (unsigned int)grid * block;
    if ((stride & (CH4 - 1)) == 0) {
        DiagonalLinear_80960133529733_kernel<true><<<grid, block, 0, stream>>>(
            (const f32x4*)x, (const f32x4*)diag, (f32x4*)out, n4);
    } else {
        DiagonalLinear_80960133529733_kernel<false><<<grid, block, 0, stream>>>(
            (const f32x4*)x, (const f32x4*)diag, (f32x4*)out, n4);
    }
}

// Round 6
// 209.399 us; speedup vs baseline: 1.1812x; 1.1812x over previous
//
#include <hip/hip_runtime.h>

// out = x * diag (broadcast over last axis). x: 32768 x 4096 f32, diag: 4096 f32.
// R6: R1/R4 structure (compiler-natural schedule — all manual batching
// regressed) + NONTEMPORAL STORE ONLY. Theory: 512MB output write-allocates
// in L2/L3, churning the 256MB L3 against the 512MB read stream; nt store
// bypasses the cache path. Loads stay cached (R3's nt-load+batch bundle
// regressed; batching alone reproduced the regression, so nt is unconvicted).

#define CH4 1024   // 4096 channels / 4 floats per float4

typedef float f32x4 __attribute__((ext_vector_type(4)));

template <bool HOIST>
__global__ __launch_bounds__(256)
void DiagonalLinear_80960133529733_kernel(const f32x4* __restrict__ x,
                                          const f32x4* __restrict__ diag,
                                          f32x4* __restrict__ out,
                                          unsigned int n4) {
    const unsigned int stride = gridDim.x * blockDim.x;
    unsigned int i = blockIdx.x * blockDim.x + threadIdx.x;

    f32x4 dv;
    if (HOIST) dv = diag[i & (CH4 - 1)];   // channel group constant per thread

    for (; i < n4; i += stride) {
        f32x4 xv = x[i];
        f32x4 dvv = HOIST ? dv : diag[i & (CH4 - 1)];
        __builtin_nontemporal_store(xv * dvv, &out[i]);
    }
}

extern "C" void kernel_launch(void* const* d_in, const int* in_sizes, int n_in,
                              void* d_out, int out_size, void* d_ws, size_t ws_size,
                              hipStream_t stream) {
    const float* x    = (const float*)d_in[0];
    const float* diag = (const float*)d_in[1];
    float* out        = (float*)d_out;

    const long long n  = (long long)in_sizes[0];   // 32768*4096
    const unsigned int n4 = (unsigned int)(n / 4); // 2^25, fits u32

    const int block = 256;
    long long want = ((long long)n4 + block - 1) / block;
    int grid = (int)(want < 2048 ? want : 2048);

    const unsigned int stride = (unsigned int)grid * block;
    if ((stride & (CH4 - 1)) == 0) {
        DiagonalLinear_80960133529733_kernel<true><<<grid, block, 0, stream>>>(
            (const f32x4*)x, (const f32x4*)diag, (f32x4*)out, n4);
    } else {
        DiagonalLinear_80960133529733_kernel<false><<<grid, block, 0, stream>>>(
            (const f32x4*)x, (const f32x4*)diag, (f32x4*)out, n4);
    }
}

// Round 7
// 202.976 us; speedup vs baseline: 1.2186x; 1.0316x over previous
//
#include <hip/hip_runtime.h>

// out = x * diag (broadcast over last axis). x: 32768 x 4096 f32, diag: 4096 f32.
// R7: R6 (nt-store, won +4%) + NONTEMPORAL LOAD on x. Both streams are
// single-use; bypass L2/L3 allocation on the read path too. diag load stays
// cached (reused every iteration by every wave).

#define CH4 1024   // 4096 channels / 4 floats per float4

typedef float f32x4 __attribute__((ext_vector_type(4)));

template <bool HOIST>
__global__ __launch_bounds__(256)
void DiagonalLinear_80960133529733_kernel(const f32x4* __restrict__ x,
                                          const f32x4* __restrict__ diag,
                                          f32x4* __restrict__ out,
                                          unsigned int n4) {
    const unsigned int stride = gridDim.x * blockDim.x;
    unsigned int i = blockIdx.x * blockDim.x + threadIdx.x;

    f32x4 dv;
    if (HOIST) dv = diag[i & (CH4 - 1)];   // channel group constant per thread

    for (; i < n4; i += stride) {
        f32x4 xv = __builtin_nontemporal_load(&x[i]);
        f32x4 dvv = HOIST ? dv : diag[i & (CH4 - 1)];
        __builtin_nontemporal_store(xv * dvv, &out[i]);
    }
}

extern "C" void kernel_launch(void* const* d_in, const int* in_sizes, int n_in,
                              void* d_out, int out_size, void* d_ws, size_t ws_size,
                              hipStream_t stream) {
    const float* x    = (const float*)d_in[0];
    const float* diag = (const float*)d_in[1];
    float* out        = (float*)d_out;

    const long long n  = (long long)in_sizes[0];   // 32768*4096
    const unsigned int n4 = (unsigned int)(n / 4); // 2^25, fits u32

    const int block = 256;
    long long want = ((long long)n4 + block - 1) / block;
    int grid = (int)(want < 2048 ? want : 2048);

    const unsigned int stride = (unsigned int)grid * block;
    if ((stride & (CH4 - 1)) == 0) {
        DiagonalLinear_80960133529733_kernel<true><<<grid, block, 0, stream>>>(
            (const f32x4*)x, (const f32x4*)diag, (f32x4*)out, n4);
    } else {
        DiagonalLinear_80960133529733_kernel<false><<<grid, block, 0, stream>>>(
            (const f32x4*)x, (const f32x4*)diag, (f32x4*)out, n4);
    }
}

// Round 8
// 197.621 us; speedup vs baseline: 1.2516x; 1.0271x over previous
//
#include <hip/hip_runtime.h>

// out = x * diag (broadcast over last axis). x: 32768 x 4096 f32, diag: 4096 f32.
// R8: R7 (nt load+store, cumulative +7%) + BLOCK-CONTIGUOUS CHUNK mapping.
// Theory: R5's regression was DRAM page scatter (in-flight loads 8MB apart),
// not batching per se. Block-chunk mapping keeps each block's traffic inside
// a contiguous 256KB slice -> DRAM row-buffer hits, coherent L2 streams.
// Per-instruction coalescing unchanged (lane-contiguous 4KB per access).

#define CH4 1024   // 4096 channels / 4 floats per float4

typedef float f32x4 __attribute__((ext_vector_type(4)));

// Chunked kernel: requires chunk % CH4 == 0 and n4 % chunk == 0,
// chunk = iters * 256.
__global__ __launch_bounds__(256)
void DiagonalLinear_chunked(const f32x4* __restrict__ x,
                            const f32x4* __restrict__ diag,
                            f32x4* __restrict__ out,
                            unsigned int chunk) {
    const unsigned int tid  = threadIdx.x;
    const unsigned int base = blockIdx.x * chunk + tid;
    const unsigned int iters = chunk >> 8;   // / 256

    // chunk is a multiple of 1024 -> block base is channel-aligned; each
    // thread cycles through exactly 4 channel groups (tid + j*256).
    const f32x4 d0 = diag[tid];
    const f32x4 d1 = diag[tid + 256];
    const f32x4 d2 = diag[tid + 512];
    const f32x4 d3 = diag[tid + 768];

    unsigned int idx = base;
    for (unsigned int k = 0; k < iters; k += 4, idx += 1024) {
        f32x4 a = __builtin_nontemporal_load(&x[idx]);
        __builtin_nontemporal_store(a * d0, &out[idx]);
        f32x4 b = __builtin_nontemporal_load(&x[idx + 256]);
        __builtin_nontemporal_store(b * d1, &out[idx + 256]);
        f32x4 c = __builtin_nontemporal_load(&x[idx + 512]);
        __builtin_nontemporal_store(c * d2, &out[idx + 512]);
        f32x4 d = __builtin_nontemporal_load(&x[idx + 768]);
        __builtin_nontemporal_store(d * d3, &out[idx + 768]);
    }
}

// Fallback: R7 grid-stride kernel (general shapes).
template <bool HOIST>
__global__ __launch_bounds__(256)
void DiagonalLinear_gs(const f32x4* __restrict__ x,
                       const f32x4* __restrict__ diag,
                       f32x4* __restrict__ out,
                       unsigned int n4) {
    const unsigned int stride = gridDim.x * blockDim.x;
    unsigned int i = blockIdx.x * blockDim.x + threadIdx.x;
    f32x4 dv;
    if (HOIST) dv = diag[i & (CH4 - 1)];
    for (; i < n4; i += stride) {
        f32x4 xv = __builtin_nontemporal_load(&x[i]);
        f32x4 dvv = HOIST ? dv : diag[i & (CH4 - 1)];
        __builtin_nontemporal_store(xv * dvv, &out[i]);
    }
}

extern "C" void kernel_launch(void* const* d_in, const int* in_sizes, int n_in,
                              void* d_out, int out_size, void* d_ws, size_t ws_size,
                              hipStream_t stream) {
    const float* x    = (const float*)d_in[0];
    const float* diag = (const float*)d_in[1];
    float* out        = (float*)d_out;

    const long long n  = (long long)in_sizes[0];   // 32768*4096
    const unsigned int n4 = (unsigned int)(n / 4); // 2^25, fits u32

    const int block = 256;
    const int grid  = 2048;
    const unsigned int chunk = n4 / grid;          // 16384 float4 per block

    // Chunked path needs: even division, chunk multiple of CH4, iters mult of 4.
    if ((long long)grid * chunk == (long long)n4 &&
        (chunk & (CH4 - 1)) == 0 && ((chunk >> 8) & 3) == 0) {
        DiagonalLinear_chunked<<<grid, block, 0, stream>>>(
            (const f32x4*)x, (const f32x4*)diag, (f32x4*)out, chunk);
    } else {
        long long want = ((long long)n4 + block - 1) / block;
        int g = (int)(want < 2048 ? want : 2048);
        const unsigned int stride = (unsigned int)g * block;
        if ((stride & (CH4 - 1)) == 0) {
            DiagonalLinear_gs<true><<<g, block, 0, stream>>>(
                (const f32x4*)x, (const f32x4*)diag, (f32x4*)out, n4);
        } else {
            DiagonalLinear_gs<false><<<g, block, 0, stream>>>(
                (const f32x4*)x, (const f32x4*)diag, (f32x4*)out, n4);
        }
    }
}